// Round 1
// baseline (130.139 us; speedup 1.0000x reference)
//
#include <hip/hip_runtime.h>

// SOM/PSO hybrid update, MI355X.
// N = 256*256 = 65536 particles, DIM = 512, fp32 everything.
// Pass 1: argmin of squared distance (wave-per-row, block partials).
// Pass 2: 1-block min-reduce of partials -> encoded (distbits<<32)|idx.
// Pass 3: masked PSO update (wave-per-row; unmasked rows copy and skip r1/r2).

constexpr int DIM   = 512;
constexpr int NPART = 256 * 256;
constexpr int THREADS = 256;
constexpr int WPB = THREADS / 64;      // waves per block
constexpr int DIST_BLOCKS = 2048;

__global__ __launch_bounds__(THREADS)
void som_dist(const float* __restrict__ input,
              const float* __restrict__ particles,
              unsigned long long* __restrict__ partials) {
    const int lane = threadIdx.x & 63;
    const int wave = threadIdx.x >> 6;
    const int gwave  = blockIdx.x * WPB + wave;
    const int nwaves = gridDim.x * WPB;

    const float4* in4 = (const float4*)input;
    const float4 i0 = in4[lane];        // floats [lane*4 .. lane*4+3]
    const float4 i1 = in4[64 + lane];   // floats [256 + lane*4 ..]

    unsigned long long best = ~0ull;
    for (int row = gwave; row < NPART; row += nwaves) {
        const float4* p4 = (const float4*)(particles + (size_t)row * DIM);
        float4 p0 = p4[lane];
        float4 p1 = p4[64 + lane];
        float t, d;
        t = i0.x - p0.x; d  = t * t;
        t = i0.y - p0.y; d += t * t;
        t = i0.z - p0.z; d += t * t;
        t = i0.w - p0.w; d += t * t;
        t = i1.x - p1.x; d += t * t;
        t = i1.y - p1.y; d += t * t;
        t = i1.z - p1.z; d += t * t;
        t = i1.w - p1.w; d += t * t;
        #pragma unroll
        for (int off = 32; off >= 1; off >>= 1)
            d += __shfl_xor(d, off, 64);
        // d is now the full row sum in every lane (butterfly).
        unsigned long long enc =
            ((unsigned long long)__float_as_uint(d) << 32) | (unsigned int)row;
        best = (enc < best) ? enc : best;
    }

    __shared__ unsigned long long smin[WPB];
    if (lane == 0) smin[wave] = best;
    __syncthreads();
    if (threadIdx.x == 0) {
        unsigned long long b = smin[0];
        #pragma unroll
        for (int i = 1; i < WPB; ++i) b = (smin[i] < b) ? smin[i] : b;
        partials[blockIdx.x] = b;
    }
}

__global__ __launch_bounds__(256)
void som_reduce(const unsigned long long* __restrict__ partials,
                unsigned long long* __restrict__ out) {
    __shared__ unsigned long long s[256];
    unsigned long long b = ~0ull;
    for (int i = threadIdx.x; i < DIST_BLOCKS; i += 256) {
        unsigned long long v = partials[i];
        b = (v < b) ? v : b;
    }
    s[threadIdx.x] = b;
    __syncthreads();
    for (int off = 128; off >= 1; off >>= 1) {
        if (threadIdx.x < off) {
            unsigned long long v = s[threadIdx.x + off];
            if (v < s[threadIdx.x]) s[threadIdx.x] = v;
        }
        __syncthreads();
    }
    if (threadIdx.x == 0) out[0] = s[0];
}

__global__ __launch_bounds__(THREADS)
void som_update(const float* __restrict__ particles,
                const float* __restrict__ velocities,
                const float* __restrict__ r1,
                const float* __restrict__ r2,
                const int*   __restrict__ grid_loc,
                const int*   __restrict__ iter_num,
                const unsigned long long* __restrict__ bmu_enc,
                float* __restrict__ out_p,
                float* __restrict__ out_v) {
    const int lane = threadIdx.x & 63;
    const int wave = threadIdx.x >> 6;
    const int row  = blockIdx.x * WPB + wave;

    const int bmu = (int)(unsigned int)(bmu_enc[0] & 0xffffffffull);
    const float decay   = 1.0f - (float)iter_num[0] * (1.0f / 100.0f);
    const float radius  = 0.3f * decay;
    const float sigma_d = 128.0f * decay;

    const int2 gl = ((const int2*)grid_loc)[row];
    const int2 bl = ((const int2*)grid_loc)[bmu];
    const float dx = (float)gl.x - (float)bl.x;
    const float dy = (float)gl.y - (float)bl.y;
    const float d2 = dx * dx + dy * dy;
    const float nb = expf(-d2 / (sigma_d * sigma_d));
    const bool upd = (1.0f - nb) <= radius;   // global_nbest == exp(0) == 1 exactly

    const size_t base = (size_t)row * DIM;
    const float4* p4 = (const float4*)(particles  + base);
    const float4* v4 = (const float4*)(velocities + base);
    float4* op4 = (float4*)(out_p + base);
    float4* ov4 = (float4*)(out_v + base);

    if (!upd) {
        // wave-uniform branch: plain copy, skip r1/r2 reads
        float4 a0 = p4[lane], a1 = p4[64 + lane];
        float4 b0 = v4[lane], b1 = v4[64 + lane];
        op4[lane] = a0; op4[64 + lane] = a1;
        ov4[lane] = b0; ov4[64 + lane] = b1;
    } else {
        const float4* g4 = (const float4*)(particles + (size_t)bmu * DIM);
        const float4* x4 = (const float4*)(r1 + base);
        const float4* y4 = (const float4*)(r2 + base);
        #pragma unroll
        for (int h = 0; h < 2; ++h) {
            const int idx = h * 64 + lane;
            float4 p = p4[idx], v = v4[idx], g = g4[idx];
            float4 a = x4[idx], b = y4[idx];
            float4 vn, po;
            float df;
            df = g.x - p.x; vn.x = 0.5f * v.x + 0.1f * a.x * df + 0.1f * b.x * df;
            df = g.y - p.y; vn.y = 0.5f * v.y + 0.1f * a.y * df + 0.1f * b.y * df;
            df = g.z - p.z; vn.z = 0.5f * v.z + 0.1f * a.z * df + 0.1f * b.z * df;
            df = g.w - p.w; vn.w = 0.5f * v.w + 0.1f * a.w * df + 0.1f * b.w * df;
            po.x = p.x + vn.x; po.y = p.y + vn.y;
            po.z = p.z + vn.z; po.w = p.w + vn.w;
            ov4[idx] = vn;
            op4[idx] = po;
        }
    }
}

extern "C" void kernel_launch(void* const* d_in, const int* in_sizes, int n_in,
                              void* d_out, int out_size, void* d_ws, size_t ws_size,
                              hipStream_t stream) {
    const float* input      = (const float*)d_in[0];
    const float* particles  = (const float*)d_in[1];
    const float* velocities = (const float*)d_in[2];
    const float* r1         = (const float*)d_in[3];
    const float* r2         = (const float*)d_in[4];
    const int*   grid_loc   = (const int*)d_in[5];
    const int*   iter_num   = (const int*)d_in[6];

    float* out_p = (float*)d_out;
    float* out_v = out_p + (size_t)NPART * DIM;

    unsigned long long* w        = (unsigned long long*)d_ws;
    unsigned long long* final_enc = w;       // w[0]
    unsigned long long* partials  = w + 8;   // 64 B in, one slot per dist block

    som_dist<<<DIST_BLOCKS, THREADS, 0, stream>>>(input, particles, partials);
    som_reduce<<<1, 256, 0, stream>>>(partials, final_enc);
    som_update<<<NPART / WPB, THREADS, 0, stream>>>(
        particles, velocities, r1, r2, grid_loc, iter_num, final_enc,
        out_p, out_v);
}